// Round 2
// 82.226 us; speedup vs baseline: 1.0576x; 1.0576x over previous
//
#include <hip/hip_runtime.h>

#define M_BASIS 100
constexpr float INV_TWO_PI = 0.15915494309189535f;

// Row = 100 floats = exactly 25 float4s (400 B, 16B-aligned per row).
// Thread t (0..249 active of 256): group = t/25 selects row offset within the
// block's 10-row batch, k = t%25 selects which float4 chunk of the row.
// k is FIXED per thread -> basis params for j = 4k..4k+3 hoisted into
// registers once (no LDS, no dynamic indexing). Each block iteration writes
// 10 rows = 4000 contiguous bytes via dwordx4 stores.
__global__ __launch_bounds__(256) void cs_kernel(
    const float* __restrict__ theta,
    const float* __restrict__ basis_mu,
    const float* __restrict__ basis_sigma,
    float* __restrict__ out,
    int N)
{
    const int tid = threadIdx.x;
    if (tid >= 250) return;
    const int grp = tid / 25;        // 0..9  (row offset within block batch)
    const int k   = tid - grp * 25;  // 0..24 (float4 chunk within row)
    const int j   = 4 * k;

    // --- hoist the 4 basis entries into registers (24 floats) ---
    float mu0[4], mu1[4];
    float s00[4], s01[4], s10[4], s11[4];
#pragma unroll
    for (int c = 0; c < 4; ++c) {
        float2 m = ((const float2*)basis_mu)[j + c];
        float4 s = ((const float4*)basis_sigma)[j + c];
        mu0[c] = m.x; mu1[c] = m.y;
        s00[c] = s.x; s01[c] = s.y; s10[c] = s.z; s11[c] = s.w;
    }

    const int rows_per_sweep = gridDim.x * 10;
    for (int row = blockIdx.x * 10 + grp; row < N; row += rows_per_sweep) {
        const float* th = theta + (size_t)row * 6;
        float2 e  = *(const float2*)(th);       // eta
        float2 qa = *(const float2*)(th + 2);   // t2, t3
        float2 qb = *(const float2*)(th + 4);   // t4, t5

        // P = -2*theta[2:6]; Sigma = sym(P^-1); Mu = Sigma @ eta
        float p00 = -2.0f * qa.x, p01 = -2.0f * qa.y;
        float p10 = -2.0f * qb.x, p11 = -2.0f * qb.y;
        float inv_detP = __builtin_amdgcn_rcpf(p00 * p11 - p01 * p10);
        float S00 = p11 * inv_detP;
        float S11 = p00 * inv_detP;
        float S01 = -0.5f * (p01 + p10) * inv_detP;
        float Mu0 = S00 * e.x + S01 * e.y;
        float Mu1 = S01 * e.x + S11 * e.y;

        // 4 independent output chains (ILP) -> one float4 store
        float r[4];
#pragma unroll
        for (int c = 0; c < 4; ++c) {
            float c00 = S00 + s00[c], c01 = S01 + s01[c];
            float c10 = S01 + s10[c], c11 = S11 + s11[c];
            float d0 = Mu0 - mu0[c], d1 = Mu1 - mu1[c];
            float detC = c00 * c11 - c01 * c10;
            float invC = __builtin_amdgcn_rcpf(detC);
            float quad = (d0 * (c11 * d0 - c01 * d1) + d1 * (c00 * d1 - c10 * d0)) * invC;
            r[c] = __expf(-0.5f * quad) * INV_TWO_PI * __builtin_amdgcn_rsqf(detC);
        }
        float4 rv = make_float4(r[0], r[1], r[2], r[3]);
        ((float4*)out)[(size_t)row * 25 + k] = rv;
    }
}

extern "C" void kernel_launch(void* const* d_in, const int* in_sizes, int n_in,
                              void* d_out, int out_size, void* d_ws, size_t ws_size,
                              hipStream_t stream) {
    const float* theta      = (const float*)d_in[0];   // [N,6]
    const float* basis_mu   = (const float*)d_in[1];   // [M,2]
    const float* basis_sig  = (const float*)d_in[2];   // [M,2,2]
    float* out = (float*)d_out;                        // [N,M]

    int N = in_sizes[0] / 6;
    // 2048 blocks = 8 blocks/CU resident, 10 rows per block iteration
    // -> ~6.4 grid-stride iterations per thread; tail handled by the loop.
    int block = 256;
    int grid = 2048;
    hipLaunchKernelGGL(cs_kernel, dim3(grid), dim3(block), 0, stream,
                       theta, basis_mu, basis_sig, out, N);
}